// Round 1
// baseline (5801.593 us; speedup 1.0000x reference)
//
#include <hip/hip_runtime.h>

// DGP RF Embeddings: X[500000,64] -> VB layer1 (64->128, ReLU RF) -> VB layer2
// (128->64) -> precision-weighted segment mean over X_idx (U=50000 segments).
// Round 1: fp32 VALU baseline, thread-per-row, atomics into d_out accumulators.

#define N_ROWS 500000
#define D_IN   64
#define NUM_RF 128
#define D_OUTD 64
#define U_SEG  50000
#define EPS_F  1e-8f
#define SCALE_F 0.125f  // sqrt(2/128) exactly

// ---- prep: transpose layer-1 weights, precompute Wmu2^2 -------------------
__global__ void prep_kernel(const float* __restrict__ Wmu1,
                            const float* __restrict__ Wvar1,
                            const float* __restrict__ Wmu2,
                            float* __restrict__ Wmu1T,
                            float* __restrict__ Wvar1T,
                            float* __restrict__ Wsq) {
    int t = blockIdx.x * blockDim.x + threadIdx.x;   // 0..8191
    if (t >= D_IN * NUM_RF) return;
    int j = t / D_IN;   // rf index 0..127
    int i = t % D_IN;   // input index 0..63
    Wmu1T[j * D_IN + i]  = Wmu1[i * NUM_RF + j];
    Wvar1T[j * D_IN + i] = Wvar1[i * NUM_RF + j];
    float w = Wmu2[t];  // Wmu2 is [128][64] row-major, same flat size
    Wsq[t] = w * w;
}

// ---- main: one thread per row --------------------------------------------
__global__ __launch_bounds__(256, 2) void fwd_kernel(
        const float* __restrict__ X,
        const int*   __restrict__ Xidx,
        const float* __restrict__ Wmu1T,
        const float* __restrict__ Wvar1T,
        const float* __restrict__ Wmu2,
        const float* __restrict__ Wvar2,
        const float* __restrict__ Wsq,
        float* __restrict__ out) {
    int r = blockIdx.x * blockDim.x + threadIdx.x;
    if (r >= N_ROWS) return;

    float x[D_IN];
    const float4* xp = (const float4*)(X + (size_t)r * D_IN);
    #pragma unroll
    for (int q = 0; q < D_IN / 4; ++q) {
        float4 v = xp[q];
        x[4*q+0] = v.x; x[4*q+1] = v.y; x[4*q+2] = v.z; x[4*q+3] = v.w;
    }

    float m2[D_OUTD], v2[D_OUTD];
    #pragma unroll
    for (int d = 0; d < D_OUTD; ++d) { m2[d] = 0.f; v2[d] = 0.f; }

    // process 2 random features per iteration (share x*x)
    #pragma unroll 1
    for (int j = 0; j < NUM_RF; j += 2) {
        float m1a = 0.f, v1a = 0.f, m1b = 0.f, v1b = 0.f;
        const float* wma = Wmu1T  + j * D_IN;
        const float* wva = Wvar1T + j * D_IN;
        const float* wmb = wma + D_IN;
        const float* wvb = wva + D_IN;
        #pragma unroll
        for (int i = 0; i < D_IN; ++i) {
            float xi  = x[i];
            float xi2 = xi * xi;
            m1a = fmaf(xi,  wma[i], m1a);
            v1a = fmaf(xi2, wva[i], v1a);
            m1b = fmaf(xi,  wmb[i], m1b);
            v1b = fmaf(xi2, wvb[i], v1b);
        }
        float ga  = m1a > 0.f ? 1.f : 0.f;
        float gb  = m1b > 0.f ? 1.f : 0.f;
        float mja = SCALE_F * (m1a > 0.f ? m1a : 0.f);
        float mjb = SCALE_F * (m1b > 0.f ? m1b : 0.f);
        float vja = (SCALE_F * SCALE_F) * v1a * ga;
        float vjb = (SCALE_F * SCALE_F) * v1b * gb;
        float aja = fmaf(mja, mja, vja);   // E[x^2] = m^2 + v
        float ajb = fmaf(mjb, mjb, vjb);

        const float* w2a  = Wmu2  + j * D_OUTD;
        const float* wv2a = Wvar2 + j * D_OUTD;
        const float* wsqa = Wsq   + j * D_OUTD;
        const float* w2b  = w2a  + D_OUTD;
        const float* wv2b = wv2a + D_OUTD;
        const float* wsqb = wsqa + D_OUTD;
        #pragma unroll
        for (int d = 0; d < D_OUTD; ++d) {
            m2[d] = fmaf(mja, w2a[d], fmaf(mjb, w2b[d], m2[d]));
            v2[d] = fmaf(aja, wv2a[d], fmaf(vja, wsqa[d], v2[d]));
            v2[d] = fmaf(ajb, wv2b[d], fmaf(vjb, wsqb[d], v2[d]));
        }
    }

    int u = Xidx[r];
    float* msum = out;                              // [U][64] accumulator
    float* wsum = out + (size_t)U_SEG * D_OUTD;     // [U][64] accumulator
    #pragma unroll
    for (int d = 0; d < D_OUTD; ++d) {
        float p = 1.0f / (v2[d] + EPS_F);           // precision
        atomicAdd(&msum[u * D_OUTD + d], p * m2[d]);
        atomicAdd(&wsum[u * D_OUTD + d], p);
    }
}

// ---- finalize: accumulators -> (mean, var_i) in place ---------------------
__global__ void finalize_kernel(float* __restrict__ out) {
    int e = blockIdx.x * blockDim.x + threadIdx.x;
    if (e >= U_SEG * D_OUTD) return;
    float msum = out[e];
    float wsum = out[U_SEG * D_OUTD + e] + EPS_F;
    float vi = 1.0f / wsum;
    out[e] = msum * vi;
    out[U_SEG * D_OUTD + e] = vi;
}

extern "C" void kernel_launch(void* const* d_in, const int* in_sizes, int n_in,
                              void* d_out, int out_size, void* d_ws, size_t ws_size,
                              hipStream_t stream) {
    const float* X     = (const float*)d_in[0];
    const int*   Xidx  = (const int*)  d_in[1];
    const float* Wmu1  = (const float*)d_in[2];
    const float* Wvar1 = (const float*)d_in[3];
    const float* Wmu2  = (const float*)d_in[4];
    const float* Wvar2 = (const float*)d_in[5];
    float* out = (float*)d_out;

    float* Wmu1T  = (float*)d_ws;            // [128][64]
    float* Wvar1T = Wmu1T  + NUM_RF * D_IN;  // [128][64]
    float* Wsq    = Wvar1T + NUM_RF * D_IN;  // [128][64]

    // zero the output accumulators (harness poisons d_out once, not per replay)
    hipMemsetAsync(d_out, 0, sizeof(float) * (size_t)out_size, stream);

    prep_kernel<<<(D_IN * NUM_RF + 255) / 256, 256, 0, stream>>>(
        Wmu1, Wvar1, Wmu2, Wmu1T, Wvar1T, Wsq);

    fwd_kernel<<<(N_ROWS + 255) / 256, 256, 0, stream>>>(
        X, Xidx, Wmu1T, Wvar1T, Wmu2, Wvar2, Wsq, out);

    finalize_kernel<<<(U_SEG * D_OUTD + 255) / 256, 256, 0, stream>>>(out);
}